// Round 1
// baseline (370.417 us; speedup 1.0000x reference)
//
#include <hip/hip_runtime.h>

#define D_EMB 768
#define NH 12
#define DK 64
#define NB 2
#define SS 4096
#define E3 (3*D_EMB)   // 2304
#define MM (NB*SS)     // 8192

typedef unsigned short u16;
typedef __attribute__((ext_vector_type(8))) __bf16 bf16x8;
typedef __attribute__((ext_vector_type(4))) float f32x4;

static __device__ __forceinline__ u16 f2bf(float f) {
  unsigned u = __builtin_bit_cast(unsigned, f);
  u += 0x7fffu + ((u >> 16) & 1u);          // round-to-nearest-even
  return (u16)(u >> 16);
}
static __device__ __forceinline__ float bf2f(u16 s) {
  unsigned u = ((unsigned)s) << 16;
  return __builtin_bit_cast(float, u);
}
static __device__ __forceinline__ f32x4 mfma16(bf16x8 a, bf16x8 b, f32x4 c) {
  return __builtin_amdgcn_mfma_f32_16x16x32_bf16(a, b, c, 0, 0, 0);
}

// ---------------- cast fp32 -> bf16, elementwise ----------------
__global__ __launch_bounds__(256) void cast_kernel(const float* __restrict__ in,
                                                   u16* __restrict__ out, int n) {
  int i = (blockIdx.x * 256 + threadIdx.x) * 4;
  if (i + 3 < n) {
    float4 v = *(const float4*)(in + i);
    out[i + 0] = f2bf(v.x);
    out[i + 1] = f2bf(v.y);
    out[i + 2] = f2bf(v.z);
    out[i + 3] = f2bf(v.w);
  }
}

// -------- transpose + cast weights: WT[n][k] = W[k][n] * scale --------
__global__ __launch_bounds__(256) void transpose_cast_w(const float* __restrict__ W,
                                                        u16* __restrict__ WT, float scale) {
  __shared__ float tile[32][33];
  int kb = blockIdx.y * 32, nb = blockIdx.x * 32;
  int tx = threadIdx.x, ty = threadIdx.y;
#pragma unroll
  for (int i = 0; i < 4; i++)
    tile[ty + i * 8][tx] = W[(size_t)(kb + ty + i * 8) * D_EMB + nb + tx];
  __syncthreads();
#pragma unroll
  for (int i = 0; i < 4; i++)
    WT[(size_t)(nb + ty + i * 8) * D_EMB + kb + tx] = f2bf(tile[tx][ty + i * 8] * scale);
}

// -------- transpose V (bf16): VT[(b*12+h)*64 + d][s] = QKV[b*4096+s][1536+h*64+d] --------
__global__ __launch_bounds__(256) void transpose_v(const u16* __restrict__ QKV,
                                                   u16* __restrict__ VT) {
  __shared__ u16 tile[32][33];
  int bh = blockIdx.z;
  int b = bh / NH, h = bh % NH;
  int sb = blockIdx.x * 32, db = blockIdx.y * 32;
  int tx = threadIdx.x, ty = threadIdx.y;
  const u16* src = QKV + (size_t)(b * SS) * E3 + 2 * D_EMB + h * DK;
  u16* dst = VT + (size_t)bh * DK * SS;
#pragma unroll
  for (int i = 0; i < 4; i++)
    tile[ty + i * 8][tx] = src[(size_t)(sb + ty + i * 8) * E3 + db + tx];
  __syncthreads();
#pragma unroll
  for (int i = 0; i < 4; i++)
    dst[(size_t)(db + ty + i * 8) * SS + sb + tx] = tile[tx][ty + i * 8];
}

// ---------------- bf16 GEMM, B given transposed: C[M][N] = A[M][K] @ Bt[N][K]^T ----------------
// block 256 = 4 waves (2x2), 128x128 tile, BK=32, mfma 16x16x32
template <int OUTF32>
__global__ __launch_bounds__(256) void gemm_bt(const u16* __restrict__ A,
                                               const u16* __restrict__ Bt,
                                               void* __restrict__ Cout,
                                               int M, int N, int K, float scale) {
  __shared__ __align__(16) u16 As[128 * 32];
  __shared__ __align__(16) u16 Bs[128 * 32];
  int tid = threadIdx.x;
  int wave = tid >> 6, lane = tid & 63;
  int g = lane >> 4, nIdx = lane & 15;
  int m0 = blockIdx.y * 128, n0 = blockIdx.x * 128;
  int wm = (wave >> 1) * 64, wn = (wave & 1) * 64;

  f32x4 acc[4][4] = {};

  int row = tid >> 2, co = (tid & 3) * 8;         // chunk for this thread (c = tid)
  int row2 = row + 64;                             // chunk c = tid + 256

  for (int k0 = 0; k0 < K; k0 += 32) {
    __syncthreads();
    uint4 a0 = *(const uint4*)(A + (size_t)(m0 + row) * K + k0 + co);
    uint4 b0 = *(const uint4*)(Bt + (size_t)(n0 + row) * K + k0 + co);
    uint4 a1 = *(const uint4*)(A + (size_t)(m0 + row2) * K + k0 + co);
    uint4 b1 = *(const uint4*)(Bt + (size_t)(n0 + row2) * K + k0 + co);
    *(uint4*)(As + row * 32 + co) = a0;
    *(uint4*)(Bs + row * 32 + co) = b0;
    *(uint4*)(As + row2 * 32 + co) = a1;
    *(uint4*)(Bs + row2 * 32 + co) = b1;
    __syncthreads();

    bf16x8 af[4], bfr[4];
#pragma unroll
    for (int i = 0; i < 4; i++)
      af[i] = *(const bf16x8*)(As + (wm + i * 16 + nIdx) * 32 + g * 8);
#pragma unroll
    for (int j = 0; j < 4; j++)
      bfr[j] = *(const bf16x8*)(Bs + (wn + j * 16 + nIdx) * 32 + g * 8);
#pragma unroll
    for (int i = 0; i < 4; i++)
#pragma unroll
      for (int j = 0; j < 4; j++)
        acc[i][j] = mfma16(af[i], bfr[j], acc[i][j]);
  }

#pragma unroll
  for (int i = 0; i < 4; i++)
#pragma unroll
    for (int j = 0; j < 4; j++)
#pragma unroll
      for (int r = 0; r < 4; r++) {
        int rr = m0 + wm + i * 16 + g * 4 + r;
        int cc = n0 + wn + j * 16 + nIdx;
        float v = acc[i][j][r] * scale;
        if (OUTF32)
          ((float*)Cout)[(size_t)rr * N + cc] = v;
        else
          ((u16*)Cout)[(size_t)rr * N + cc] = f2bf(v);
      }
}

// ---------------- flash attention (no-max online softmax) ----------------
// grid (S/64, NH, B), block 256 (4 waves, 16 q-rows each)
__global__ __launch_bounds__(256) void flash(const u16* __restrict__ QKV,
                                             const u16* __restrict__ VT,
                                             u16* __restrict__ O) {
  __shared__ __align__(16) u16 Ks[64 * 72];      // [kv][d], pad 8
  __shared__ __align__(16) u16 Vs[64 * 72];      // [d][kv], pad 8
  __shared__ __align__(16) u16 Ps[4][16 * 72];   // per wave [q][kv], pad 8

  int b = blockIdx.z, h = blockIdx.y, qt = blockIdx.x;
  int tid = threadIdx.x, wave = tid >> 6, lane = tid & 63;
  int g = lane >> 4, n = lane & 15;

  const u16* Qbase = QKV + (size_t)(b * SS + qt * 64) * E3 + h * DK;
  const u16* Kbase = QKV + (size_t)(b * SS) * E3 + D_EMB + h * DK;
  const u16* VTbase = VT + (size_t)(b * NH + h) * DK * SS;

  bf16x8 qf[2];
#pragma unroll
  for (int km = 0; km < 2; km++)
    qf[km] = *(const bf16x8*)(Qbase + (size_t)(wave * 16 + n) * E3 + km * 32 + g * 8);

  f32x4 o_acc[4] = {};
  float lsum[4] = {0.f, 0.f, 0.f, 0.f};

  u16* myP = &Ps[wave][0];
  int srow = tid >> 3, sco = (tid & 7) * 8;   // staging chunk (c = tid), rows 0..31
  int srow2 = srow + 32;                       // chunk c = tid + 256

  for (int kt = 0; kt < SS / 64; kt++) {
    __syncthreads();
    {
      uint4 k0 = *(const uint4*)(Kbase + (size_t)(kt * 64 + srow) * E3 + sco);
      uint4 v0 = *(const uint4*)(VTbase + (size_t)srow * SS + kt * 64 + sco);
      uint4 k1 = *(const uint4*)(Kbase + (size_t)(kt * 64 + srow2) * E3 + sco);
      uint4 v1 = *(const uint4*)(VTbase + (size_t)srow2 * SS + kt * 64 + sco);
      *(uint4*)(Ks + srow * 72 + sco) = k0;
      *(uint4*)(Vs + srow * 72 + sco) = v0;
      *(uint4*)(Ks + srow2 * 72 + sco) = k1;
      *(uint4*)(Vs + srow2 * 72 + sco) = v1;
    }
    __syncthreads();

    // S = Q K^T (scale already folded into Q)
    f32x4 s[4];
#pragma unroll
    for (int j = 0; j < 4; j++) {
      bf16x8 kf0 = *(const bf16x8*)(Ks + (j * 16 + n) * 72 + g * 8);
      bf16x8 kf1 = *(const bf16x8*)(Ks + (j * 16 + n) * 72 + 32 + g * 8);
      f32x4 t = {};
      t = mfma16(qf[0], kf0, t);
      t = mfma16(qf[1], kf1, t);
      s[j] = t;
    }

    // P = exp(S); accumulate lane-local row sums; stash P (bf16) to LDS
#pragma unroll
    for (int j = 0; j < 4; j++)
#pragma unroll
      for (int r = 0; r < 4; r++) {
        float p = __expf(s[j][r]);
        u16 pb = f2bf(p);
        myP[(g * 4 + r) * 72 + j * 16 + n] = pb;
        lsum[r] += bf2f(pb);
      }
    __syncthreads();

    // O += P @ V
    bf16x8 pf[2];
#pragma unroll
    for (int km = 0; km < 2; km++)
      pf[km] = *(const bf16x8*)(myP + n * 72 + km * 32 + g * 8);
#pragma unroll
    for (int dt = 0; dt < 4; dt++) {
      bf16x8 vf0 = *(const bf16x8*)(Vs + (dt * 16 + n) * 72 + g * 8);
      bf16x8 vf1 = *(const bf16x8*)(Vs + (dt * 16 + n) * 72 + 32 + g * 8);
      o_acc[dt] = mfma16(pf[0], vf0, o_acc[dt]);
      o_acc[dt] = mfma16(pf[1], vf1, o_acc[dt]);
    }
  }

  // reduce row sums across the 16 lanes holding each row group
#pragma unroll
  for (int off = 1; off < 16; off <<= 1)
#pragma unroll
    for (int r = 0; r < 4; r++)
      lsum[r] += __shfl_xor(lsum[r], off);

  u16* Obase = O + (size_t)(b * SS + qt * 64 + wave * 16) * D_EMB + h * DK;
#pragma unroll
  for (int dt = 0; dt < 4; dt++)
#pragma unroll
    for (int r = 0; r < 4; r++) {
      float v = o_acc[dt][r] / lsum[r];
      Obase[(size_t)(g * 4 + r) * D_EMB + dt * 16 + n] = f2bf(v);
    }
}

extern "C" void kernel_launch(void* const* d_in, const int* in_sizes, int n_in,
                              void* d_out, int out_size, void* d_ws, size_t ws_size,
                              hipStream_t stream) {
  const float* X  = (const float*)d_in[0];
  const float* Wq = (const float*)d_in[1];
  const float* Wk = (const float*)d_in[2];
  const float* Wv = (const float*)d_in[3];
  const float* Wo = (const float*)d_in[4];
  float* out = (float*)d_out;

  u16* Xb    = (u16*)d_ws;                         // MM*D_EMB
  u16* WTqkv = Xb + (size_t)MM * D_EMB;            // E3*D_EMB
  u16* WoT   = WTqkv + (size_t)E3 * D_EMB;         // D_EMB*D_EMB
  u16* QKV   = WoT + (size_t)D_EMB * D_EMB;        // MM*E3
  u16* VT    = QKV + (size_t)MM * E3;              // NB*NH*DK*SS
  u16* Ob    = VT + (size_t)NB * NH * DK * SS;     // MM*D_EMB

  dim3 tb(32, 8);
  cast_kernel<<<(MM * D_EMB) / 1024, 256, 0, stream>>>(X, Xb, MM * D_EMB);
  // fold 1/sqrt(dk)=0.125 into Wq (exact power-of-two scale)
  transpose_cast_w<<<dim3(24, 24), tb, 0, stream>>>(Wq, WTqkv, 0.125f);
  transpose_cast_w<<<dim3(24, 24), tb, 0, stream>>>(Wk, WTqkv + (size_t)D_EMB * D_EMB, 1.0f);
  transpose_cast_w<<<dim3(24, 24), tb, 0, stream>>>(Wv, WTqkv + (size_t)2 * D_EMB * D_EMB, 1.0f);
  transpose_cast_w<<<dim3(24, 24), tb, 0, stream>>>(Wo, WoT, 1.0f);

  gemm_bt<0><<<dim3(E3 / 128, MM / 128), 256, 0, stream>>>(Xb, WTqkv, (void*)QKV,
                                                           MM, E3, D_EMB, 1.0f);
  transpose_v<<<dim3(SS / 32, 2, NB * NH), tb, 0, stream>>>(QKV, VT);
  flash<<<dim3(SS / 64, NH, NB), 256, 0, stream>>>(QKV, VT, Ob);
  gemm_bt<1><<<dim3(D_EMB / 128, MM / 128), 256, 0, stream>>>(Ob, WoT, (void*)out,
                                                              MM, D_EMB, D_EMB, 1.0f);
}